// Round 4
// baseline (380.099 us; speedup 1.0000x reference)
//
#include <hip/hip_runtime.h>
#include <hip/hip_bf16.h>

// out[B,S,D_OUT] = x @ sign(W)^T + bias  ==  GEMM M=8192, N=4096, K=4096.
// Round 4: 8-phase software-pipelined 256x256 kernel. Each phase: <=4 ds_read
// (next phase's operands) + ~1 global_load_lds + barrier + 8 MFMA. Reads are
// issued one phase ahead so compiler-counted lgkmcnt waits overlap LDS drain
// with MFMA. Uniform vmcnt(6); 1 barrier/phase; snake cell order.

#define M_DIM 8192
#define N_DIM 4096
#define K_DIM 4096
#define BM 256
#define BN 256
#define BK 64
#define NT (K_DIM / BK)  // 64

typedef __attribute__((ext_vector_type(8))) short bf16x8;
typedef __attribute__((ext_vector_type(4))) float f32x4;
typedef __attribute__((ext_vector_type(8))) unsigned short u16x8;

// ---------- conversion helpers ----------

__device__ __forceinline__ unsigned short f2bf_rne(float f) {
    unsigned u = __float_as_uint(f);
    unsigned r = (u + 0x7FFFu + ((u >> 16) & 1u)) >> 16;
    return (unsigned short)r;
}

__device__ __forceinline__ unsigned short sign_bf(float f) {
    if (f == 0.0f) return 0;
    return (unsigned short)(0x3F80u | ((__float_as_uint(f) >> 16) & 0x8000u));
}

__global__ __launch_bounds__(256) void cvt_x_kernel(
    const float* __restrict__ in, unsigned short* __restrict__ out, long nvec8) {
    long i = (long)blockIdx.x * blockDim.x + threadIdx.x;
    if (i >= nvec8) return;
    const float4* p = reinterpret_cast<const float4*>(in) + i * 2;
    float4 v0 = p[0];
    float4 v1 = p[1];
    u16x8 r;
    r[0] = f2bf_rne(v0.x); r[1] = f2bf_rne(v0.y);
    r[2] = f2bf_rne(v0.z); r[3] = f2bf_rne(v0.w);
    r[4] = f2bf_rne(v1.x); r[5] = f2bf_rne(v1.y);
    r[6] = f2bf_rne(v1.z); r[7] = f2bf_rne(v1.w);
    reinterpret_cast<u16x8*>(out)[i] = r;
}

__global__ __launch_bounds__(256) void cvt_w_kernel(
    const float* __restrict__ in, unsigned short* __restrict__ out, long nvec8) {
    long i = (long)blockIdx.x * blockDim.x + threadIdx.x;
    if (i >= nvec8) return;
    const float4* p = reinterpret_cast<const float4*>(in) + i * 2;
    float4 v0 = p[0];
    float4 v1 = p[1];
    u16x8 r;
    r[0] = sign_bf(v0.x); r[1] = sign_bf(v0.y);
    r[2] = sign_bf(v0.z); r[3] = sign_bf(v0.w);
    r[4] = sign_bf(v1.x); r[5] = sign_bf(v1.y);
    r[6] = sign_bf(v1.z); r[7] = sign_bf(v1.w);
    reinterpret_cast<u16x8*>(out)[i] = r;
}

// ---------- async global->LDS ----------

__device__ __forceinline__ void GL16(const unsigned short* g, unsigned short* l) {
    __builtin_amdgcn_global_load_lds(
        (const __attribute__((address_space(1))) unsigned int*)g,
        (__attribute__((address_space(3))) unsigned int*)l, 16, 0, 0);
}

// ---------- MFMA cell: 2x2 fragment pairs x 2 k-halves = 8 MFMA ----------

template<int AM, int AN>
__device__ __forceinline__ void cell(f32x4 (&acc)[8][4],
                                     const bf16x8 (&av)[2][2],
                                     const bf16x8 (&bv)[2][2]) {
#pragma unroll
    for (int i = 0; i < 2; ++i)
#pragma unroll
        for (int j = 0; j < 2; ++j)
#pragma unroll
            for (int kk = 0; kk < 2; ++kk)
                acc[AM + i][AN + j] = __builtin_amdgcn_mfma_f32_16x16x32_bf16(
                    av[i][kk], bv[j][kk], acc[AM + i][AN + j], 0, 0, 0);
}

// ---------- 8-phase pipelined GEMM ----------
// 512 thr = 8 waves (2M x 4N); wave out 128x64 = acc[8][4] f32x4.
// a-pairs A0..A3 (m{01,23,45,67}), b-pairs B0(n01), B1(n23).
// Cells:  p0 A0B0  p1 A1B0  p2 A1B1  p3 A0B1  p4 A2B1  p5 A3B1  p6 A3B0  p7 A2B0
// Regs:   aY<-A0(loaded prev p6), aZ<-A1@p0, aZ<-A2@p3, aX<-A3@p4, aY<-A0'@p6,
//         bB0<-B0(prev p7, post-MFMA), bB1<-B1@p1.
// Stages (1-2 GL16/phase): p0 SA1(t+1) p1 SB1ab(t+1) p3 SA2(t+1) p4 SA3(t+1)
//         p5 SA0(t+2) p6 SB0ab(t+2).  Every read's unit staged >=8 phases back;
//         vmcnt(6) at phase top + barrier publishes cross-wave.

#define VM6 asm volatile("s_waitcnt vmcnt(6)" ::: "memory")
#define BARW __builtin_amdgcn_s_barrier()
#define PRIO1 __builtin_amdgcn_s_setprio(1)
#define PRIO0 __builtin_amdgcn_s_setprio(0)

__global__ __launch_bounds__(512, 2) void gemm256p(
    const unsigned short* __restrict__ A,   // [M][K] bf16 bits
    const unsigned short* __restrict__ Bt,  // [N][K] bf16 bits (sign weights)
    const float* __restrict__ bias,         // [N]
    float* __restrict__ C)                  // [M][N] fp32
{
    __shared__ __align__(16) unsigned short As[2][BM * BK];  // 64 KiB
    __shared__ __align__(16) unsigned short Bs[2][BN * BK];  // 64 KiB

    const int tid  = threadIdx.x;
    const int lane = tid & 63;
    const int w    = tid >> 6;
    const int wr   = w >> 2;
    const int wc   = w & 3;

    // T1: XCD-aware bijective swizzle (grid = 512, divisible by 8)
    int bid = blockIdx.x;
    const int cpx = gridDim.x >> 3;
    bid = (bid & 7) * cpx + (bid >> 3);
    const int ntile = N_DIM / BN;  // 16
    const long brow = (long)(bid / ntile) * BM;
    const long bcol = (long)(bid % ntile) * BN;

    // staging lane geometry (same inverse-swizzle as R2/R3, conflict-free)
    const int wrow8 = lane >> 3;
    const int colsw = ((lane & 7) ^ wrow8) * 8;
    const int arw_u = (w >> 2) * 128 + (w & 3) * 8;  // wave-uniform A row base
    const int brw_u = (w >> 2) * 64 + (w & 3) * 8;   // wave-uniform B row base
    const long aRow = brow + arw_u + wrow8;
    const long bRow = bcol + brw_u + wrow8;

#define GA(BUF, I, KT) GL16(A  + (aRow + (I) * 32) * (long)K_DIM + (colsw + (KT)), \
                            &As[BUF][(arw_u + (I) * 32) * 64])
#define GB(BUF, OFS, KT) GL16(Bt + (bRow + (OFS)) * (long)K_DIM + (colsw + (KT)), \
                              &Bs[BUF][(brw_u + (OFS)) * 64])

    // fragment read addressing (swizzled, identical to R2/R3)
    const int fr = lane & 15;
    const int fq = lane >> 4;
    const int rqu = (fq * 8) ^ ((lane & 7) << 3);
    const int a_base = (wr * 128 + fr) * 64 + rqu;
    const int b_base = (wc * 64 + fr) * 64 + rqu;

#define RA(DST, BUF, MB) do { \
    (DST)[0][0] = *reinterpret_cast<const bf16x8*>(&As[BUF][ (a_base + (MB) * 1024)            ]); \
    (DST)[0][1] = *reinterpret_cast<const bf16x8*>(&As[BUF][ (a_base + (MB) * 1024) ^ 32       ]); \
    (DST)[1][0] = *reinterpret_cast<const bf16x8*>(&As[BUF][ (a_base + ((MB) + 1) * 1024)      ]); \
    (DST)[1][1] = *reinterpret_cast<const bf16x8*>(&As[BUF][ (a_base + ((MB) + 1) * 1024) ^ 32 ]); } while (0)

#define RB(DST, BUF, NB) do { \
    (DST)[0][0] = *reinterpret_cast<const bf16x8*>(&Bs[BUF][ (b_base + (NB) * 1024)            ]); \
    (DST)[0][1] = *reinterpret_cast<const bf16x8*>(&Bs[BUF][ (b_base + (NB) * 1024) ^ 32       ]); \
    (DST)[1][0] = *reinterpret_cast<const bf16x8*>(&Bs[BUF][ (b_base + ((NB) + 1) * 1024)      ]); \
    (DST)[1][1] = *reinterpret_cast<const bf16x8*>(&Bs[BUF][ (b_base + ((NB) + 1) * 1024) ^ 32 ]); } while (0)

    f32x4 acc[8][4];
#pragma unroll
    for (int m = 0; m < 8; ++m)
#pragma unroll
        for (int n = 0; n < 4; ++n) acc[m][n] = (f32x4){0.f, 0.f, 0.f, 0.f};

    bf16x8 aX[2][2], aY[2][2], aZ[2][2], bB0[2][2], bB1[2][2];

    // ----- prologue: tile0 (8 units) + tile1's {SA0, SB0a, SB0b} -----
    GA(0, 0, 0); GA(0, 1, 0); GA(0, 2, 0); GA(0, 3, 0);
    GB(0, 0, 0); GB(0, 128, 0); GB(0, 32, 0); GB(0, 160, 0);
    GA(1, 0, BK); GB(1, 0, BK); GB(1, 128, BK);
    asm volatile("s_waitcnt vmcnt(3)" ::: "memory");  // tile0 landed
    BARW;
    RA(aY, 0, 0);   // A0(t=0)
    RB(bB0, 0, 0);  // B0(t=0)

#define TILE_BODY(CUR, NXT, TT) { \
    const int kt1 = ((TT) + 1) * BK, kt2 = ((TT) + 2) * BK; \
    const bool s1 = ((TT) + 1 < NT), s2 = ((TT) + 2 < NT); \
    /* p0 */ VM6; RA(aZ, CUR, 2); if (s1) GA(NXT, 1, kt1); BARW; \
    PRIO1; cell<0, 0>(acc, aY, bB0); PRIO0; \
    /* p1 */ VM6; RB(bB1, CUR, 2); if (s1) { GB(NXT, 32, kt1); GB(NXT, 160, kt1); } BARW; \
    PRIO1; cell<2, 0>(acc, aZ, bB0); PRIO0; \
    /* p2 */ VM6; BARW; \
    PRIO1; cell<2, 2>(acc, aZ, bB1); PRIO0; \
    /* p3 */ VM6; RA(aZ, CUR, 4); if (s1) GA(NXT, 2, kt1); BARW; \
    PRIO1; cell<0, 2>(acc, aY, bB1); PRIO0; \
    /* p4 */ VM6; RA(aX, CUR, 6); if (s1) GA(NXT, 3, kt1); BARW; \
    PRIO1; cell<4, 2>(acc, aZ, bB1); PRIO0; \
    /* p5 */ VM6; if (s2) GA(CUR, 0, kt2); BARW; \
    PRIO1; cell<6, 2>(acc, aX, bB1); PRIO0; \
    /* p6 */ VM6; if (s1) RA(aY, NXT, 0); if (s2) { GB(CUR, 0, kt2); GB(CUR, 128, kt2); } BARW; \
    PRIO1; cell<6, 0>(acc, aX, bB0); PRIO0; \
    /* p7 */ VM6; BARW; \
    PRIO1; cell<4, 0>(acc, aZ, bB0); PRIO0; \
    if (s1) RB(bB0, NXT, 0); \
}

    for (int t = 0; t < NT; t += 2) {
        TILE_BODY(0, 1, t);
        TILE_BODY(1, 0, t + 1);
    }
#undef TILE_BODY

    // ----- epilogue: C/D layout col = lane&15, row = (lane>>4)*4 + j -----
#pragma unroll
    for (int n = 0; n < 4; ++n) {
        const long cg = bcol + wc * 64 + n * 16 + fr;
        const float bv = bias[cg];
#pragma unroll
        for (int m = 0; m < 8; ++m) {
            const long rbase = brow + wr * 128 + m * 16 + fq * 4;
#pragma unroll
            for (int j = 0; j < 4; ++j)
                C[(rbase + j) * (long)N_DIM + cg] = acc[m][n][j] + bv;
        }
    }
}

// ---------- naive fallback ----------

__global__ __launch_bounds__(256) void naive_kernel(
    const float* __restrict__ x, const float* __restrict__ w,
    const float* __restrict__ bias, float* __restrict__ out, long total) {
    long gid = (long)blockIdx.x * blockDim.x + threadIdx.x;
    if (gid >= total) return;
    long m = gid / N_DIM, n = gid % N_DIM;
    const float* xr = x + m * (long)K_DIM;
    const float* wr = w + n * (long)K_DIM;
    float s = 0.f;
    for (int k = 0; k < K_DIM; ++k) {
        float wv = wr[k];
        float sg = (wv > 0.f) ? 1.f : ((wv < 0.f) ? -1.f : 0.f);
        s += xr[k] * sg;
    }
    out[gid] = s + bias[n];
}

// ---------- launch ----------

extern "C" void kernel_launch(void* const* d_in, const int* in_sizes, int n_in,
                              void* d_out, int out_size, void* d_ws, size_t ws_size,
                              hipStream_t stream) {
    const float* x    = (const float*)d_in[0];
    const float* w    = (const float*)d_in[1];
    const float* bias = (const float*)d_in[2];
    float* out = (float*)d_out;

    const size_t nA = (size_t)M_DIM * K_DIM;
    const size_t nB = (size_t)N_DIM * K_DIM;
    const size_t need_bytes = (nA + nB) * sizeof(unsigned short);

    if (ws_size >= need_bytes) {
        unsigned short* xb = (unsigned short*)d_ws;
        unsigned short* wb = xb + nA;
        {
            long nvec8 = (long)(nA / 8);
            cvt_x_kernel<<<(int)((nvec8 + 255) / 256), 256, 0, stream>>>(x, xb, nvec8);
        }
        {
            long nvec8 = (long)(nB / 8);
            cvt_w_kernel<<<(int)((nvec8 + 255) / 256), 256, 0, stream>>>(w, wb, nvec8);
        }
        dim3 grid((M_DIM / BM) * (N_DIM / BN));  // 512
        gemm256p<<<grid, 512, 0, stream>>>(xb, wb, bias, out);
    } else {
        long total = (long)M_DIM * N_DIM;
        naive_kernel<<<(int)((total + 255) / 256), 256, 0, stream>>>(x, w, bias, out, total);
    }
}

// Round 7
// 308.338 us; speedup vs baseline: 1.2327x; 1.2327x over previous
//
#include <hip/hip_runtime.h>
#include <hip/hip_bf16.h>

// out[B,S,D_OUT] = x @ sign(W)^T + bias  ==  GEMM M=8192, N=4096, K=4096.
// Round 7: asm-pipelined 4-phase K-loop at R2 register pressure.
// R5/R6 NaN root cause: 36 live asm-def'd frags (~290 regs) vs 256 cap ->
// regalloc splits/spills read ds_read dests before lgkm wait (no HW interlock).
// Fix: 24 frags with disjoint live ranges (peak 16 live = 64 VGPR, = R2),
// full-drain waits only (lgkmcnt(0); one vmcnt(0)/K-tile), rule-18 sched
// barriers. Batches b23/a47/b01 issued 1 phase ahead (drain under MFMA);
// only a03's 8 reads are same-phase exposed.

#define M_DIM 8192
#define N_DIM 4096
#define K_DIM 4096
#define BM 256
#define BN 256
#define BK 64
#define NT (K_DIM / BK)  // 64

typedef __attribute__((ext_vector_type(8))) short bf16x8;
typedef __attribute__((ext_vector_type(4))) float f32x4;
typedef __attribute__((ext_vector_type(8))) unsigned short u16x8;

// ---------- conversion helpers ----------

__device__ __forceinline__ unsigned short f2bf_rne(float f) {
    unsigned u = __float_as_uint(f);
    unsigned r = (u + 0x7FFFu + ((u >> 16) & 1u)) >> 16;
    return (unsigned short)r;
}

__device__ __forceinline__ unsigned short sign_bf(float f) {
    if (f == 0.0f) return 0;
    return (unsigned short)(0x3F80u | ((__float_as_uint(f) >> 16) & 0x8000u));
}

__global__ __launch_bounds__(256) void cvt_x_kernel(
    const float* __restrict__ in, unsigned short* __restrict__ out, long nvec8) {
    long i = (long)blockIdx.x * blockDim.x + threadIdx.x;
    if (i >= nvec8) return;
    const float4* p = reinterpret_cast<const float4*>(in) + i * 2;
    float4 v0 = p[0];
    float4 v1 = p[1];
    u16x8 r;
    r[0] = f2bf_rne(v0.x); r[1] = f2bf_rne(v0.y);
    r[2] = f2bf_rne(v0.z); r[3] = f2bf_rne(v0.w);
    r[4] = f2bf_rne(v1.x); r[5] = f2bf_rne(v1.y);
    r[6] = f2bf_rne(v1.z); r[7] = f2bf_rne(v1.w);
    reinterpret_cast<u16x8*>(out)[i] = r;
}

__global__ __launch_bounds__(256) void cvt_w_kernel(
    const float* __restrict__ in, unsigned short* __restrict__ out, long nvec8) {
    long i = (long)blockIdx.x * blockDim.x + threadIdx.x;
    if (i >= nvec8) return;
    const float4* p = reinterpret_cast<const float4*>(in) + i * 2;
    float4 v0 = p[0];
    float4 v1 = p[1];
    u16x8 r;
    r[0] = sign_bf(v0.x); r[1] = sign_bf(v0.y);
    r[2] = sign_bf(v0.z); r[3] = sign_bf(v0.w);
    r[4] = sign_bf(v1.x); r[5] = sign_bf(v1.y);
    r[6] = sign_bf(v1.z); r[7] = sign_bf(v1.w);
    reinterpret_cast<u16x8*>(out)[i] = r;
}

// ---------- async global->LDS ----------

__device__ __forceinline__ void GL16(const unsigned short* g, unsigned short* l) {
    __builtin_amdgcn_global_load_lds(
        (const __attribute__((address_space(1))) unsigned int*)g,
        (__attribute__((address_space(3))) unsigned int*)l, 16, 0, 0);
}

// ---------- inline-asm ds_read_b128 with immediate byte offset ----------

template<int OFS>
__device__ __forceinline__ bf16x8 DSR(const unsigned short* p) {
    bf16x8 r;
    auto lp = (const __attribute__((address_space(3))) unsigned short*)p;
    asm volatile("ds_read_b128 %0, %1 offset:%2"
                 : "=&v"(r) : "v"(lp), "i"(OFS));
    return r;
}

#define BARRIER asm volatile("s_barrier" ::: "memory")
#define VMCNT0  asm volatile("s_waitcnt vmcnt(0)" ::: "memory")
#define LGKM0   asm volatile("s_waitcnt lgkmcnt(0)" ::: "memory")
#define SCHED0  __builtin_amdgcn_sched_barrier(0)
#define PRIO1   __builtin_amdgcn_s_setprio(1)
#define PRIO0   __builtin_amdgcn_s_setprio(0)

// 16-MFMA quadrant: 4 m-frags x 2 n-frags x 2 k-halves
#define CELL(MB, NB, Aa, Bb) \
    _Pragma("unroll") for (int m_ = 0; m_ < 4; ++m_) \
    _Pragma("unroll") for (int n_ = 0; n_ < 2; ++n_) \
    _Pragma("unroll") for (int kk_ = 0; kk_ < 2; ++kk_) \
        acc[(MB) + m_][(NB) + n_] = __builtin_amdgcn_mfma_f32_16x16x32_bf16( \
            Aa[m_][kk_], Bb[n_][kk_], acc[(MB) + m_][(NB) + n_], 0, 0, 0)

// ---------- 256x256 4-phase GEMM, reads 1 phase ahead, full-drain waits ----
// 512 thr = 8 waves (2M x 4N); wave out 128x64 = acc[8][4] f32x4 (AGPRs).
// Per K-tile t (CUR=t&1):
//  ph1: bar | stage B23(t+1)->NXT | rd a03(t) | lgkm0 | Q1=a03*b01 | rd b23(t)
//  ph2: bar | stage A03+A47(t+1)->NXT        | lgkm0 | Q2=a03*b23 | rd a47(t)
//  ph3: vmcnt0 (tile t+1 fully staged) | bar | lgkm0 | Q3=a47*b01 | rd b01(t+1)
//  ph4: bar | stage B01(t+2)->CUR            |         Q4=a47*b23
// b23/a47/b01 drain under the following MFMA cluster; only a03 is exposed.
// Live ranges: a03 ph1..Q2, a47 ph2e..Q4 (overlay); b01 ph3e..Q3(next);
// b23 ph1e..Q4 -> peak 16 frags = 64 VGPR (R2-equal; no spill).

__global__ __launch_bounds__(512, 2) void gemm256d(
    const unsigned short* __restrict__ A,   // [M][K] bf16 bits
    const unsigned short* __restrict__ Bt,  // [N][K] bf16 bits (sign weights)
    const float* __restrict__ bias,         // [N]
    float* __restrict__ C)                  // [M][N] fp32
{
    __shared__ __align__(16) unsigned short As[2][BM * BK];  // 64 KiB
    __shared__ __align__(16) unsigned short Bs[2][BN * BK];  // 64 KiB

    const int tid  = threadIdx.x;
    const int lane = tid & 63;
    const int w    = tid >> 6;
    const int wr   = w >> 2;
    const int wc   = w & 3;

    // T1: XCD-aware bijective swizzle (grid = 512, divisible by 8)
    int bid = blockIdx.x;
    const int cpx = gridDim.x >> 3;
    bid = (bid & 7) * cpx + (bid >> 3);
    const int ntile = N_DIM / BN;  // 16
    const long brow = (long)(bid / ntile) * BM;
    const long bcol = (long)(bid % ntile) * BN;

    // staging lane geometry (inverse-swizzled global src, linear LDS dest)
    const int wrow8 = lane >> 3;
    const int colsw = ((lane & 7) ^ wrow8) * 8;
    const int arw_u = (w >> 2) * 128 + (w & 3) * 8;
    const int brw_u = (w >> 2) * 64 + (w & 3) * 8;
    const long aRow = brow + arw_u + wrow8;
    const long bRow = bcol + brw_u + wrow8;

#define GA(BUF, I, KT) GL16(A  + (aRow + (I) * 32) * (long)K_DIM + (colsw + (KT)), \
                            &As[BUF][(arw_u + (I) * 32) * 64])
#define GB(BUF, OFS, KT) GL16(Bt + (bRow + (OFS)) * (long)K_DIM + (colsw + (KT)), \
                              &Bs[BUF][(brw_u + (OFS)) * 64])

    // fragment read bases (swizzled), loop-invariant
    const int fr = lane & 15;
    const int fq = lane >> 4;
    const int rqu = (fq * 8) ^ ((lane & 7) << 3);
    const int aoff = (wr * 128 + fr) * 64 + rqu;
    const int boff = (wc * 64 + fr) * 64 + rqu;

    const unsigned short* As0k0 = &As[0][aoff];
    const unsigned short* As0k1 = &As[0][aoff ^ 32];
    const unsigned short* As1k0 = &As[1][aoff];
    const unsigned short* As1k1 = &As[1][aoff ^ 32];
    const unsigned short* Bs0k0 = &Bs[0][boff];
    const unsigned short* Bs0k1 = &Bs[0][boff ^ 32];
    const unsigned short* Bs1k0 = &Bs[1][boff];
    const unsigned short* Bs1k1 = &Bs[1][boff ^ 32];

    f32x4 acc[8][4];
#pragma unroll
    for (int m = 0; m < 8; ++m)
#pragma unroll
        for (int n = 0; n < 4; ++n) acc[m][n] = (f32x4){0.f, 0.f, 0.f, 0.f};

    bf16x8 a03[4][2], a47[4][2], b01[2][2], b23[2][2];

    // ----- prologue: tile0 (8 GL16 -> buf0) + tile1's B01 (2 -> buf1) -----
    GA(0, 0, 0); GA(0, 1, 0); GA(0, 2, 0); GA(0, 3, 0);
    GB(0, 0, 0); GB(0, 128, 0); GB(0, 32, 0); GB(0, 160, 0);
    GB(1, 0, BK); GB(1, 128, BK);
    VMCNT0;
    BARRIER;
    // pre-issue b01(t=0); certified at ph1(0)'s lgkm0
    b01[0][0] = DSR<0>(Bs0k0);    b01[0][1] = DSR<0>(Bs0k1);
    b01[1][0] = DSR<2048>(Bs0k0); b01[1][1] = DSR<2048>(Bs0k1);

#define TILE_BODY(TT, CUR, NXT, pAc0, pAc1, pBc0, pBc1, pBn0, pBn1) { \
    const long kt1 = (long)((TT) + 1) * BK; \
    const long kt2 = (long)((TT) + 2) * BK; \
    const bool s1 = ((TT) + 1 < NT); \
    const bool s2 = ((TT) + 2 < NT); \
    /* ---- ph1 ---- */ \
    BARRIER; \
    if (s1) { GB(NXT, 32, kt1); GB(NXT, 160, kt1); } \
    a03[0][0] = DSR<0>(pAc0);    a03[0][1] = DSR<0>(pAc1); \
    a03[1][0] = DSR<2048>(pAc0); a03[1][1] = DSR<2048>(pAc1); \
    a03[2][0] = DSR<4096>(pAc0); a03[2][1] = DSR<4096>(pAc1); \
    a03[3][0] = DSR<6144>(pAc0); a03[3][1] = DSR<6144>(pAc1); \
    LGKM0; SCHED0; \
    PRIO1; CELL(0, 0, a03, b01); PRIO0; SCHED0; \
    b23[0][0] = DSR<4096>(pBc0); b23[0][1] = DSR<4096>(pBc1); \
    b23[1][0] = DSR<6144>(pBc0); b23[1][1] = DSR<6144>(pBc1); \
    /* ---- ph2 ---- */ \
    BARRIER; \
    if (s1) { GA(NXT, 0, kt1); GA(NXT, 1, kt1); GA(NXT, 2, kt1); GA(NXT, 3, kt1); } \
    LGKM0; SCHED0; \
    PRIO1; CELL(0, 2, a03, b23); PRIO0; SCHED0; \
    a47[0][0] = DSR<8192>(pAc0);  a47[0][1] = DSR<8192>(pAc1); \
    a47[1][0] = DSR<10240>(pAc0); a47[1][1] = DSR<10240>(pAc1); \
    a47[2][0] = DSR<12288>(pAc0); a47[2][1] = DSR<12288>(pAc1); \
    a47[3][0] = DSR<14336>(pAc0); a47[3][1] = DSR<14336>(pAc1); \
    /* ---- ph3: tile t+1 fully staged -> drain + publish ---- */ \
    VMCNT0; \
    BARRIER; \
    LGKM0; SCHED0; \
    PRIO1; CELL(4, 0, a47, b01); PRIO0; SCHED0; \
    if (s1) { \
        b01[0][0] = DSR<0>(pBn0);    b01[0][1] = DSR<0>(pBn1); \
        b01[1][0] = DSR<2048>(pBn0); b01[1][1] = DSR<2048>(pBn1); \
    } \
    /* ---- ph4 ---- */ \
    BARRIER; \
    if (s2) { GB(CUR, 0, kt2); GB(CUR, 128, kt2); } \
    PRIO1; CELL(4, 2, a47, b23); PRIO0; SCHED0; \
}

    for (int t = 0; t < NT; t += 2) {
        TILE_BODY(t,     0, 1, As0k0, As0k1, Bs0k0, Bs0k1, Bs1k0, Bs1k1);
        TILE_BODY(t + 1, 1, 0, As1k0, As1k1, Bs1k0, Bs1k1, Bs0k0, Bs0k1);
    }
#undef TILE_BODY

    // ----- epilogue: C/D layout col = lane&15, row = (lane>>4)*4 + j -----
#pragma unroll
    for (int n = 0; n < 4; ++n) {
        const long cg = bcol + wc * 64 + n * 16 + fr;
        const float bv = bias[cg];
#pragma unroll
        for (int m = 0; m < 8; ++m) {
            const long rbase = brow + wr * 128 + m * 16 + fq * 4;
#pragma unroll
            for (int j = 0; j < 4; ++j)
                C[(rbase + j) * (long)N_DIM + cg] = acc[m][n][j] + bv;
        }
    }
}

// ---------- naive fallback ----------

__global__ __launch_bounds__(256) void naive_kernel(
    const float* __restrict__ x, const float* __restrict__ w,
    const float* __restrict__ bias, float* __restrict__ out, long total) {
    long gid = (long)blockIdx.x * blockDim.x + threadIdx.x;
    if (gid >= total) return;
    long m = gid / N_DIM, n = gid % N_DIM;
    const float* xr = x + m * (long)K_DIM;
    const float* wr = w + n * (long)K_DIM;
    float s = 0.f;
    for (int k = 0; k < K_DIM; ++k) {
        float wv = wr[k];
        float sg = (wv > 0.f) ? 1.f : ((wv < 0.f) ? -1.f : 0.f);
        s += xr[k] * sg;
    }
    out[gid] = s + bias[n];
}

// ---------- launch ----------

extern "C" void kernel_launch(void* const* d_in, const int* in_sizes, int n_in,
                              void* d_out, int out_size, void* d_ws, size_t ws_size,
                              hipStream_t stream) {
    const float* x    = (const float*)d_in[0];
    const float* w    = (const float*)d_in[1];
    const float* bias = (const float*)d_in[2];
    float* out = (float*)d_out;

    const size_t nA = (size_t)M_DIM * K_DIM;
    const size_t nB = (size_t)N_DIM * K_DIM;
    const size_t need_bytes = (nA + nB) * sizeof(unsigned short);

    if (ws_size >= need_bytes) {
        unsigned short* xb = (unsigned short*)d_ws;
        unsigned short* wb = xb + nA;
        {
            long nvec8 = (long)(nA / 8);
            cvt_x_kernel<<<(int)((nvec8 + 255) / 256), 256, 0, stream>>>(x, xb, nvec8);
        }
        {
            long nvec8 = (long)(nB / 8);
            cvt_w_kernel<<<(int)((nvec8 + 255) / 256), 256, 0, stream>>>(w, wb, nvec8);
        }
        dim3 grid((M_DIM / BM) * (N_DIM / BN));  // 512
        gemm256d<<<grid, 512, 0, stream>>>(xb, wb, bias, out);
    } else {
        long total = (long)M_DIM * N_DIM;
        naive_kernel<<<(int)((total + 255) / 256), 256, 0, stream>>>(x, w, bias, out, total);
    }
}